// Round 3
// baseline (264.574 us; speedup 1.0000x reference)
//
#include <hip/hip_runtime.h>
#include <math.h>

// RiemannianLayerNormV2: x (8,4096,1025) f32 -> out (8,4096,1025) f32
// One wave (64 lanes) per row; 4 rows per 256-thread block.
// xs (1024 f32) held in 16 VGPRs/lane; 3 wave-local shfl reductions; no LDS.

#define NROWS (8 * 4096)
#define DD 1024
#define KPL 16              // elements per lane = 1024 / 64
#define WAVES_PB 4
#define BLOCK (WAVES_PB * 64)

__device__ __forceinline__ float sanitize_f(float x) {
    if (__builtin_isnan(x)) return 0.0f;
    if (__builtin_isinf(x)) return x > 0.0f ? 10000.0f : -10000.0f;
    return x;
}

__device__ __forceinline__ float wave_reduce_sum(float v) {
#pragma unroll
    for (int off = 32; off >= 1; off >>= 1)
        v += __shfl_xor(v, off, 64);
    return v;
}

__global__ void __launch_bounds__(BLOCK)
rln_kernel(const float* __restrict__ x, const float* __restrict__ gamma,
           const float* __restrict__ beta, float* __restrict__ out) {
    const int wave = threadIdx.x >> 6;
    const int lane = threadIdx.x & 63;
    const int row  = blockIdx.x * WAVES_PB + wave;
    if (row >= NROWS) return;
    const size_t base = (size_t)row * (DD + 1);

    // ---- pass 1: load x0 + xs (registers), fused (sum, sumsq) reduction ----
    float x0 = sanitize_f(x[base]);   // same-address: broadcast, cached
    float xv[KPL];
    float s_sum = 0.0f, s_sq = 0.0f;
#pragma unroll
    for (int k = 0; k < KPL; ++k) {
        float t = sanitize_f(x[base + 1 + lane + k * 64]);
        xv[k] = t;
        s_sum += t;
        s_sq  += t * t;
    }
#pragma unroll
    for (int off = 32; off >= 1; off >>= 1) {   // interleaved 2-value reduce
        s_sum += __shfl_xor(s_sum, off, 64);
        s_sq  += __shfl_xor(s_sq,  off, 64);
    }

    const float dist    = acoshf(fmaxf(x0, 1.0000001192092896f)); // clip(x0, 1+1e-7)
    const float xs_norm = fmaxf(sqrtf(s_sq), 1e-7f);
    const float s       = dist / xs_norm;          // finite: dist finite, xs_norm>=1e-7
    const float mu      = s * s_sum * (1.0f / DD); // mean(v) = s * mean(xs)

    // ---- pass 2 (registers): var = mean((v-mu)^2) ----
    float acc = 0.0f;
#pragma unroll
    for (int k = 0; k < KPL; ++k) {
        float d = s * xv[k] - mu;   // v finite => sanitize(v) is a no-op
        acc += d * d;
    }
    acc = wave_reduce_sum(acc);
    const float rstd = rsqrtf(acc * (1.0f / DD) + 1e-5f);

    // ---- pass 3 (registers): v_norm = clip((v-mu)*rstd*g + b, +-5); n^2 ----
    float nsq = 0.0f;
#pragma unroll
    for (int k = 0; k < KPL; ++k) {
        const int j = lane + k * 64;
        float vn = (s * xv[k] - mu) * rstd * gamma[j] + beta[j];
        vn = fminf(fmaxf(vn, -5.0f), 5.0f);
        xv[k] = vn;
        nsq += vn * vn;
    }
    nsq = wave_reduce_sum(nsq);
    const float n   = sqrtf(nsq);
    const float n_c = fminf(fmaxf(n, 1e-7f), 1.5f);
    const float ss  = sinhf(n_c) / fmaxf(n, 1e-7f);

    // ---- write: xs_out = ss * v_norm; x0_out = sqrt(1 + ss^2 * n^2) ----
#pragma unroll
    for (int k = 0; k < KPL; ++k)
        out[base + 1 + lane + k * 64] = sanitize_f(ss * xv[k]);
    if (lane == 0)
        out[base] = sanitize_f(sqrtf(1.0f + ss * ss * nsq));
}

extern "C" void kernel_launch(void* const* d_in, const int* in_sizes, int n_in,
                              void* d_out, int out_size, void* d_ws, size_t ws_size,
                              hipStream_t stream) {
    const float* x     = (const float*)d_in[0];
    const float* gamma = (const float*)d_in[1];
    const float* beta  = (const float*)d_in[2];
    float* out = (float*)d_out;
    const int grid = NROWS / WAVES_PB;  // 8192 blocks
    rln_kernel<<<grid, BLOCK, 0, stream>>>(x, gamma, beta, out);
}

// Round 6
// 231.505 us; speedup vs baseline: 1.1428x; 1.1428x over previous
//
#include <hip/hip_runtime.h>
#include <math.h>

// RiemannianLayerNormV2: x (8,4096,1025) f32 -> out (8,4096,1025) f32
// One wave per row, 4 rows / 256-thread block. xs in 16 VGPRs/lane.
// R6 = R5 resubmitted (container infra failure; kernel never ran).
//  - var from first-pass moments (reduction tree #2 deleted)
//  - DPP wave reductions (VALU) instead of shfl_xor (LDS pipe)
//  - gamma/beta staged in LDS per block
//  - output sanitize dropped (provably no-op: outputs bounded)

#define NROWS (8 * 4096)
#define DD 1024
#define KPL 16              // 1024 / 64
#define WAVES_PB 4
#define BLOCK (WAVES_PB * 64)

__device__ __forceinline__ float sanitize_in(float x) {
    // nan->0, +inf->1e4, -inf->-1e4, finite passthrough
    if (!__builtin_isfinite(x)) x = __builtin_isnan(x) ? 0.0f : (x > 0.0f ? 1.0e4f : -1.0e4f);
    return x;
}

template <int CTRL, int ROW_MASK>
__device__ __forceinline__ float dpp_add(float x) {
    int y = __builtin_amdgcn_update_dpp(0, __builtin_bit_cast(int, x),
                                        CTRL, ROW_MASK, 0xf, false);
    return x + __builtin_bit_cast(float, y);
}

// 64-lane sum, result broadcast to all lanes (readlane 63 -> SGPR)
__device__ __forceinline__ float wave_sum(float x) {
    x = dpp_add<0x111, 0xf>(x);  // row_shr:1
    x = dpp_add<0x112, 0xf>(x);  // row_shr:2
    x = dpp_add<0x114, 0xf>(x);  // row_shr:4
    x = dpp_add<0x118, 0xf>(x);  // row_shr:8  -> lane15 of each row16 = row sum
    x = dpp_add<0x142, 0xa>(x);  // row_bcast:15 -> rows 1,3
    x = dpp_add<0x143, 0xc>(x);  // row_bcast:31 -> row 3; lane63 = total
    return __builtin_bit_cast(float, __builtin_amdgcn_readlane(__builtin_bit_cast(int, x), 63));
}

__global__ void __launch_bounds__(BLOCK)
rln_kernel(const float* __restrict__ x, const float* __restrict__ gamma,
           const float* __restrict__ beta, float* __restrict__ out) {
    __shared__ float s_g[DD];
    __shared__ float s_b[DD];
#pragma unroll
    for (int i = 0; i < DD / BLOCK; ++i) {      // 4 iters, coalesced
        s_g[threadIdx.x + i * BLOCK] = gamma[threadIdx.x + i * BLOCK];
        s_b[threadIdx.x + i * BLOCK] = beta[threadIdx.x + i * BLOCK];
    }
    __syncthreads();

    const int wave = threadIdx.x >> 6;
    const int lane = threadIdx.x & 63;
    const int row  = blockIdx.x * WAVES_PB + wave;   // grid exact: row < NROWS
    const size_t base = (size_t)row * (DD + 1);
    const float* __restrict__ xr  = x + base + 1;
    float* __restrict__ outr      = out + base + 1;

    // ---- pass 1: load x0 + xs, fused (sum, sumsq) ----
    float x0 = sanitize_in(x[base]);             // same-address broadcast
    float xv[KPL];
    float p_sum = 0.0f, p_sq = 0.0f;
#pragma unroll
    for (int k = 0; k < KPL; ++k) {
        float t = sanitize_in(xr[lane + k * 64]);
        xv[k] = t;
        p_sum += t;
        p_sq  = fmaf(t, t, p_sq);
    }
    const float sum   = wave_sum(p_sum);
    const float sumsq = wave_sum(p_sq);

    const float dist = acoshf(fmaxf(x0, 1.0000001192092896f));  // clip(x0, 1+1e-7)
    const float rn   = fmaxf(sqrtf(sumsq), 1e-7f);
    const float s    = dist / rn;
    const float mu   = s * sum * (1.0f / DD);    // mean(v) = s * mean(xs)
    // var = mean(v^2) - mu^2 = s^2 * sumsq/D - mu^2   (mu^2 << var here)
    const float var  = fmaf(s * s, sumsq * (1.0f / DD), -mu * mu);
    const float rstd = rsqrtf(var + 1e-5f);

    // ---- pass 2 (regs): v_norm + clip, accumulate n^2 ----
    float nsq = 0.0f;
#pragma unroll
    for (int k = 0; k < KPL; ++k) {
        const int j = lane + k * 64;             // LDS: 2 lanes/bank -> free
        float t  = fmaf(s, xv[k], -mu) * rstd;
        float vn = fmaf(t, s_g[j], s_b[j]);
        vn = fminf(fmaxf(vn, -5.0f), 5.0f);      // med3
        xv[k] = vn;
        nsq = fmaf(vn, vn, nsq);
    }
    nsq = wave_sum(nsq);

    const float n  = sqrtf(nsq);
    const float nc = fminf(fmaxf(n, 1e-7f), 1.5f);
    const float ss = sinhf(nc) / fmaxf(n, 1e-7f);

    // ---- write (sanitize provably no-op: |ss*vn| bounded, x0_out finite) ----
#pragma unroll
    for (int k = 0; k < KPL; ++k)
        outr[lane + k * 64] = ss * xv[k];
    if (lane == 0)
        out[base] = sqrtf(fmaf(ss * ss, nsq, 1.0f));
}

extern "C" void kernel_launch(void* const* d_in, const int* in_sizes, int n_in,
                              void* d_out, int out_size, void* d_ws, size_t ws_size,
                              hipStream_t stream) {
    const float* x     = (const float*)d_in[0];
    const float* gamma = (const float*)d_in[1];
    const float* beta  = (const float*)d_in[2];
    float* out = (float*)d_out;
    rln_kernel<<<NROWS / WAVES_PB, BLOCK, 0, stream>>>(x, gamma, beta, out);
}